// Round 2
// baseline (4514.693 us; speedup 1.0000x reference)
//
#include <hip/hip_runtime.h>
#include <math.h>

// ---------------------------------------------------------------------------
// MLPEncoder (NRI encoder, factor=True) on MI355X — round 1: fp32, low-ws.
//   h1 = MLP1(inputs[3200,200])                        (fp32 small)
//   x2 = fusedMLP2([h1[send]|h1[recv]])  [316800,256]  (bf16, ws bigX)
//   incoming[bn] = sum_{e in 99bn..+99} x2[e]/9900     (fp32 small)
//   h3 = MLP3(incoming)                                (fp32 small)
//   x4 = fusedMLP4([h3[send]|h3[recv]|x2]) IN-PLACE over bigX
//   out = BN(x4)@fcW+fcb  (BN+fc folded into per-channel affine)
// Workspace: 162.2 MB bigX + 3 x 3.28 MB + 4 KB  ≈ 172 MB (round 0 used 341).
// ---------------------------------------------------------------------------

typedef unsigned short ushort_t;

#define E_EDGES 9900
#define NNODE   100
#define BATCH   32
#define HID     256
#define M_BIG   (BATCH * E_EDGES)   /* 316800 */
#define M_SMALL (BATCH * NNODE)     /* 3200   */

__device__ __forceinline__ float bf2f(ushort_t u) {
    union { unsigned int i; float f; } v; v.i = ((unsigned int)u) << 16; return v.f;
}
__device__ __forceinline__ ushort_t f2bf(float f) {
    union { float f; unsigned int i; } v; v.f = f;
    return (ushort_t)((v.i + 0x7fffu + ((v.i >> 16) & 1u)) >> 16);   // RNE
}
__device__ __forceinline__ float elu_f(float x) {
    return x > 0.f ? x : (expf(x) - 1.f);
}

#define FMA_ROW(ri, xs) \
    acc[ri][0] = fmaf(xs, w.x, acc[ri][0]); \
    acc[ri][1] = fmaf(xs, w.y, acc[ri][1]); \
    acc[ri][2] = fmaf(xs, w.z, acc[ri][2]); \
    acc[ri][3] = fmaf(xs, w.w, acc[ri][3]);

// ---- small fp32 GEMM: Y[3200,256] = ELU(X[3200,K1] @ W + b) ---------------
__global__ __launch_bounds__(256, 3)
void mlp_gemm_f32(const float* __restrict__ X, const float* __restrict__ W,
                  const float* __restrict__ bias, float* __restrict__ Y, int K1)
{
    __shared__ float Xs[32][68];
    __shared__ float Ws[32][256];
    const int tid = threadIdx.x;
    const int Rbase = blockIdx.x * 64;
    const int c0 = (tid & 63) * 4;
    const int r0 = (tid >> 6) * 16;
    const int r_st = tid & 63;
    const int kb = (tid >> 6) * 8;

    float acc[16][4];
    #pragma unroll
    for (int i = 0; i < 16; ++i)
        #pragma unroll
        for (int j = 0; j < 4; ++j) acc[i][j] = 0.f;

    const int nch = (K1 + 31) >> 5;
    for (int kc = 0; kc < nch; ++kc) {
        if (kc) __syncthreads();
        {   // stage X chunk transposed (guarded for K1=200 tails)
            int kg = kc * 32 + kb;
            const float* p = X + (size_t)r_st * K1 + (size_t)Rbase * K1 + kg;
            float v[8];
            if (kg + 8 <= K1) {
                float4 a = *(const float4*)p;
                float4 b = *(const float4*)(p + 4);
                v[0]=a.x; v[1]=a.y; v[2]=a.z; v[3]=a.w;
                v[4]=b.x; v[5]=b.y; v[6]=b.z; v[7]=b.w;
            } else {
                #pragma unroll
                for (int j = 0; j < 8; ++j) v[j] = (kg + j < K1) ? p[j] : 0.f;
            }
            #pragma unroll
            for (int j = 0; j < 8; ++j) Xs[kb + j][r_st] = v[j];
        }
        #pragma unroll
        for (int m = 0; m < 8; ++m) {   // stage W chunk
            int f  = tid + m * 256;
            int kk = f >> 6;
            int cc = (f & 63) * 4;
            int kg = kc * 32 + kk;
            float4 w = (kg < K1) ? *(const float4*)&W[(size_t)kg * 256 + cc]
                                 : make_float4(0.f, 0.f, 0.f, 0.f);
            *(float4*)&Ws[kk][cc] = w;
        }
        __syncthreads();
        #pragma unroll 8
        for (int kk = 0; kk < 32; ++kk) {
            float4 w = *(const float4*)&Ws[kk][c0];
            #pragma unroll
            for (int i = 0; i < 4; ++i) {
                float4 x = *(const float4*)&Xs[kk][r0 + 4 * i];
                FMA_ROW(4 * i + 0, x.x)
                FMA_ROW(4 * i + 1, x.y)
                FMA_ROW(4 * i + 2, x.z)
                FMA_ROW(4 * i + 3, x.w)
            }
        }
    }
    float4 bv = *(const float4*)&bias[c0];
    #pragma unroll
    for (int i = 0; i < 16; ++i) {
        int R = Rbase + r0 + i;
        *(float4*)&Y[(size_t)R * 256 + c0] = make_float4(
            elu_f(acc[i][0] + bv.x), elu_f(acc[i][1] + bv.y),
            elu_f(acc[i][2] + bv.z), elu_f(acc[i][3] + bv.w));
    }
}

// ---- fused 2-layer MLP over 64 edge rows ----------------------------------
// MODE 2: L1 input = [h1[send] | h1[recv]]            (K1=512)
// MODE 3: L1 input = [h3[send] | h3[recv] | x2[R]]    (K1=768), Y may == X2
// L1 hidden parked in LDS (bf16), L2 (K=256) consumes it. Output bf16.
template<int MODE>
__global__ __launch_bounds__(256, 2)
void fused_mlp(const float* __restrict__ G,
               const ushort_t* __restrict__ X2,
               const float* __restrict__ W1, const float* __restrict__ b1,
               const float* __restrict__ W2, const float* __restrict__ b2,
               ushort_t* __restrict__ Y)
{
    constexpr int K1 = (MODE == 2) ? 512 : 768;
    __shared__ float Xs[32][68];        // K-major X chunk (68: 16B-aligned rows)
    __shared__ float Ws[32][256];       // W chunk
    __shared__ ushort_t Hb[64][264];    // L1 hidden, bf16 (264: 16B-aligned rows)
    __shared__ int offS[64], offR[64];

    const int tid = threadIdx.x;
    const int Rbase = blockIdx.x * 64;
    if (tid < 64) {
        int R = Rbase + tid;
        int b = R / E_EDGES;
        int e = R - b * E_EDGES;
        int i = e / 99;                      // receiver
        int kk = e - i * 99;
        int j = kk + (kk >= i ? 1 : 0);      // sender
        offS[tid] = (b * NNODE + j) * HID;
        offR[tid] = (b * NNODE + i) * HID;
    }
    __syncthreads();

    const int c0 = (tid & 63) * 4;    // column base (lane)
    const int r0 = (tid >> 6) * 16;   // row base (wave)
    const int r_st = tid & 63;        // staging row
    const int kb = (tid >> 6) * 8;    // staging k base
    const int oS = offS[r_st], oR = offR[r_st];
    const ushort_t* x2row = X2 + (size_t)(Rbase + r_st) * 256;

    float acc[16][4];
    #pragma unroll
    for (int i = 0; i < 16; ++i)
        #pragma unroll
        for (int j = 0; j < 4; ++j) acc[i][j] = 0.f;

    // ---------------- layer 1 ----------------
    for (int kc = 0; kc < K1 / 32; ++kc) {
        if (kc) __syncthreads();
        {
            int kg = kc * 32 + kb;
            float v[8];
            if (MODE == 3 && kg >= 512) {
                union { uint4 q; ushort_t s[8]; } u;
                u.q = *(const uint4*)(x2row + (kg - 512));
                #pragma unroll
                for (int j = 0; j < 8; ++j) v[j] = bf2f(u.s[j]);
            } else {
                const float* p = (kg < 256) ? (G + oS + kg) : (G + oR + (kg - 256));
                float4 a = *(const float4*)p;
                float4 b = *(const float4*)(p + 4);
                v[0]=a.x; v[1]=a.y; v[2]=a.z; v[3]=a.w;
                v[4]=b.x; v[5]=b.y; v[6]=b.z; v[7]=b.w;
            }
            #pragma unroll
            for (int j = 0; j < 8; ++j) Xs[kb + j][r_st] = v[j];
        }
        #pragma unroll
        for (int m = 0; m < 8; ++m) {   // stage W1 chunk (K1 multiple of 32)
            int f  = tid + m * 256;
            int kk = f >> 6;
            int cc = (f & 63) * 4;
            *(float4*)&Ws[kk][cc] = *(const float4*)&W1[(size_t)(kc * 32 + kk) * 256 + cc];
        }
        __syncthreads();
        #pragma unroll 8
        for (int kk = 0; kk < 32; ++kk) {
            float4 w = *(const float4*)&Ws[kk][c0];
            #pragma unroll
            for (int i = 0; i < 4; ++i) {
                float4 x = *(const float4*)&Xs[kk][r0 + 4 * i];
                FMA_ROW(4 * i + 0, x.x)
                FMA_ROW(4 * i + 1, x.y)
                FMA_ROW(4 * i + 2, x.z)
                FMA_ROW(4 * i + 3, x.w)
            }
        }
    }
    // hidden = ELU(acc + b1) -> Hb (bf16); thread owns rows r0..r0+15, cols c0..c0+3
    {
        float4 bv = *(const float4*)&b1[c0];
        #pragma unroll
        for (int i = 0; i < 16; ++i) {
            ushort4 u;
            u.x = f2bf(elu_f(acc[i][0] + bv.x));
            u.y = f2bf(elu_f(acc[i][1] + bv.y));
            u.z = f2bf(elu_f(acc[i][2] + bv.z));
            u.w = f2bf(elu_f(acc[i][3] + bv.w));
            *(ushort4*)&Hb[r0 + i][c0] = u;
        }
    }
    // ---------------- layer 2 (K=256) ----------------
    #pragma unroll
    for (int i = 0; i < 16; ++i)
        #pragma unroll
        for (int j = 0; j < 4; ++j) acc[i][j] = 0.f;

    for (int kc = 0; kc < 8; ++kc) {
        __syncthreads();    // kc=0: Hb writes visible; all: Xs/Ws reuse safe
        {
            union { uint4 q; ushort_t s[8]; } u;
            u.q = *(const uint4*)&Hb[r_st][kc * 32 + kb];
            #pragma unroll
            for (int j = 0; j < 8; ++j) Xs[kb + j][r_st] = bf2f(u.s[j]);
        }
        #pragma unroll
        for (int m = 0; m < 8; ++m) {   // stage W2 chunk
            int f  = tid + m * 256;
            int kk = f >> 6;
            int cc = (f & 63) * 4;
            *(float4*)&Ws[kk][cc] = *(const float4*)&W2[(size_t)(kc * 32 + kk) * 256 + cc];
        }
        __syncthreads();
        #pragma unroll 8
        for (int kk = 0; kk < 32; ++kk) {
            float4 w = *(const float4*)&Ws[kk][c0];
            #pragma unroll
            for (int i = 0; i < 4; ++i) {
                float4 x = *(const float4*)&Xs[kk][r0 + 4 * i];
                FMA_ROW(4 * i + 0, x.x)
                FMA_ROW(4 * i + 1, x.y)
                FMA_ROW(4 * i + 2, x.z)
                FMA_ROW(4 * i + 3, x.w)
            }
        }
    }
    {
        float4 bv = *(const float4*)&b2[c0];
        #pragma unroll
        for (int i = 0; i < 16; ++i) {
            int R = Rbase + r0 + i;
            ushort4 u;
            u.x = f2bf(elu_f(acc[i][0] + bv.x));
            u.y = f2bf(elu_f(acc[i][1] + bv.y));
            u.z = f2bf(elu_f(acc[i][2] + bv.z));
            u.w = f2bf(elu_f(acc[i][3] + bv.w));
            *(ushort4*)&Y[(size_t)R * 256 + c0] = u;
        }
    }
}

// ---- edge2node: incoming[bn] = sum of 99 consecutive edge rows / 9900 -----
__global__ __launch_bounds__(256)
void e2n_kernel(const ushort_t* __restrict__ x2, float* __restrict__ incoming)
{
    int bn = blockIdx.x;
    int c  = threadIdx.x;
    const ushort_t* p = x2 + (size_t)bn * 99 * 256 + c;
    float s0 = 0.f, s1 = 0.f, s2 = 0.f, s3 = 0.f;
    int k = 0;
    for (; k + 4 <= 99; k += 4) {
        s0 += bf2f(p[(size_t)(k + 0) * 256]);
        s1 += bf2f(p[(size_t)(k + 1) * 256]);
        s2 += bf2f(p[(size_t)(k + 2) * 256]);
        s3 += bf2f(p[(size_t)(k + 3) * 256]);
    }
    for (; k < 99; ++k) s0 += bf2f(p[(size_t)k * 256]);
    incoming[(size_t)bn * 256 + c] = (s0 + s1 + s2 + s3) * (1.f / 9900.f);
}

// ---- BN stats: per-channel sum / sumsq over 316800 rows -------------------
__global__ __launch_bounds__(256)
void stats_kernel(const ushort_t* __restrict__ x4, float* __restrict__ stats)
{
    int c = threadIdx.x;
    int rows_per = (M_BIG + gridDim.x - 1) / gridDim.x;
    int r0 = blockIdx.x * rows_per;
    int r1 = min(r0 + rows_per, M_BIG);
    float s = 0.f, q = 0.f;
    for (int r = r0; r < r1; ++r) {
        float v = bf2f(x4[(size_t)r * 256 + c]);
        s += v;
        q = fmaf(v, v, q);
    }
    atomicAdd(&stats[c], s);
    atomicAdd(&stats[256 + c], q);
}

// ---- fold BN + fc into Wfold[256][2], bfold[2] ----------------------------
__global__ __launch_bounds__(256)
void fold_kernel(const float* __restrict__ stats,
                 const float* __restrict__ gamma, const float* __restrict__ beta,
                 const float* __restrict__ fcW, const float* __restrict__ fcb,
                 float* __restrict__ fold)
{
    __shared__ float red0[256], red1[256];
    int c = threadIdx.x;
    float mean  = stats[c] * (1.f / M_BIG);
    float var   = stats[256 + c] * (1.f / M_BIG) - mean * mean;
    float inv   = rsqrtf(var + 1e-5f);
    float scale = inv * gamma[c];
    float sh    = beta[c] - mean * scale;
    float w0 = fcW[c * 2 + 0], w1 = fcW[c * 2 + 1];
    fold[c * 2 + 0] = scale * w0;
    fold[c * 2 + 1] = scale * w1;
    red0[c] = sh * w0;
    red1[c] = sh * w1;
    __syncthreads();
    for (int off = 128; off > 0; off >>= 1) {
        if (c < off) { red0[c] += red0[c + off]; red1[c] += red1[c + off]; }
        __syncthreads();
    }
    if (c == 0) {
        fold[512] = red0[0] + fcb[0];
        fold[513] = red1[0] + fcb[1];
    }
}

// ---- final: out[R][2] = x4_row . Wfold + bfold  (wave per row) ------------
__global__ __launch_bounds__(256)
void final_kernel(const ushort_t* __restrict__ x4, const float* __restrict__ fold,
                  float* __restrict__ out)
{
    int tid  = threadIdx.x;
    int lane = tid & 63;
    int wave = tid >> 6;
    int R = blockIdx.x * 4 + wave;
    int c0 = lane * 4;
    union { uint2 q; ushort_t s[4]; } u;
    u.q = *(const uint2*)(x4 + (size_t)R * 256 + c0);
    float a0 = 0.f, a1 = 0.f;
    #pragma unroll
    for (int j = 0; j < 4; ++j) {
        float v = bf2f(u.s[j]);
        a0 = fmaf(v, fold[(c0 + j) * 2 + 0], a0);
        a1 = fmaf(v, fold[(c0 + j) * 2 + 1], a1);
    }
    #pragma unroll
    for (int off = 32; off > 0; off >>= 1) {
        a0 += __shfl_down(a0, off);
        a1 += __shfl_down(a1, off);
    }
    if (lane == 0) {
        out[(size_t)R * 2 + 0] = a0 + fold[512];
        out[(size_t)R * 2 + 1] = a1 + fold[513];
    }
}

extern "C" void kernel_launch(void* const* d_in, const int* in_sizes, int n_in,
                              void* d_out, int out_size, void* d_ws, size_t ws_size,
                              hipStream_t stream)
{
    (void)in_sizes; (void)n_in; (void)out_size; (void)ws_size;

    const float* inputs = (const float*)d_in[0];
    // d_in[1] = rel_rec, d_in[2] = rel_send: structure replaced by arithmetic.
    const float* m1W1 = (const float*)d_in[3];
    const float* m1b1 = (const float*)d_in[4];
    const float* m1W2 = (const float*)d_in[5];
    const float* m1b2 = (const float*)d_in[6];
    const float* m2W1 = (const float*)d_in[7];
    const float* m2b1 = (const float*)d_in[8];
    const float* m2W2 = (const float*)d_in[9];
    const float* m2b2 = (const float*)d_in[10];
    const float* m3W1 = (const float*)d_in[11];
    const float* m3b1 = (const float*)d_in[12];
    const float* m3W2 = (const float*)d_in[13];
    const float* m3b2 = (const float*)d_in[14];
    const float* m4W1 = (const float*)d_in[15];
    const float* m4b1 = (const float*)d_in[16];
    const float* m4W2 = (const float*)d_in[17];
    const float* m4b2 = (const float*)d_in[18];
    const float* gamma = (const float*)d_in[19];
    const float* beta  = (const float*)d_in[20];
    const float* fcW   = (const float*)d_in[21];
    const float* fcb   = (const float*)d_in[22];
    float* out = (float*)d_out;

    // ---- workspace layout (~172 MB total) ----
    char* ws = (char*)d_ws;
    const size_t BIGB  = (size_t)M_BIG * 256 * 2;     // 162,201,600 B
    const size_t SMALL = (size_t)M_SMALL * 256 * 4;   // 3,276,800 B
    ushort_t* bigX  = (ushort_t*)ws;                  // x2, then x4 in-place
    float* bufP     = (float*)(ws + BIGB);            // h1a, then h3a
    float* bufQ     = (float*)(ws + BIGB + SMALL);    // h1,  then h3
    float* bufI     = (float*)(ws + BIGB + 2 * SMALL);// incoming
    float* stats    = (float*)(ws + BIGB + 3 * SMALL);// 512 f32
    float* fold     = stats + 512;                    // 514 f32

    hipMemsetAsync(stats, 0, 2048, stream);

    dim3 blk(256);
    // MLP1: inputs[3200,200] -> bufP -> bufQ (= h1)
    mlp_gemm_f32<<<M_SMALL / 64, blk, 0, stream>>>(inputs, m1W1, m1b1, bufP, 200);
    mlp_gemm_f32<<<M_SMALL / 64, blk, 0, stream>>>(bufP,   m1W2, m1b2, bufQ, 256);
    // fused MLP2: gather h1 -> x2 (bigX)
    fused_mlp<2><<<M_BIG / 64, blk, 0, stream>>>(bufQ, bigX, m2W1, m2b1, m2W2, m2b2, bigX);
    // edge2node -> incoming ; MLP3 -> bufP -> bufQ (= h3)
    e2n_kernel<<<M_SMALL, blk, 0, stream>>>(bigX, bufI);
    mlp_gemm_f32<<<M_SMALL / 64, blk, 0, stream>>>(bufI, m3W1, m3b1, bufP, 256);
    mlp_gemm_f32<<<M_SMALL / 64, blk, 0, stream>>>(bufP, m3W2, m3b2, bufQ, 256);
    // fused MLP4: gather h3 + skip x2 -> x4 (in-place over bigX)
    fused_mlp<3><<<M_BIG / 64, blk, 0, stream>>>(bufQ, bigX, m4W1, m4b1, m4W2, m4b2, bigX);
    // BN stats -> fold -> final linear
    stats_kernel<<<1024, blk, 0, stream>>>(bigX, stats);
    fold_kernel<<<1, blk, 0, stream>>>(stats, gamma, beta, fcW, fcb, fold);
    final_kernel<<<M_BIG / 4, blk, 0, stream>>>(bigX, fold, out);
}

// Round 3
// 1131.342 us; speedup vs baseline: 3.9906x; 3.9906x over previous
//
#include <hip/hip_runtime.h>
#include <math.h>

// ---------------------------------------------------------------------------
// MLPEncoder (NRI encoder) on MI355X — round 3: MFMA bf16 for the big MLPs.
//   h1  = MLP1(inputs[3200,200])                 fp32 vector GEMM (small)
//   x2  = fusedMLP2([h1b[send]|h1b[recv]])       MFMA bf16, epilogue fuses e2n
//   h3  = MLP3(incoming/9900)                    fp32 vector GEMM (small)
//   x4  = fusedMLP4([h3b[send]|h3b[recv]|x2])    MFMA bf16 in-place, fuses BN stats
//   out = fold(BN,fc) applied to x4
// Weights for big MLPs pre-converted to bf16 transposed WT[col][K] so
// B-fragments are direct 16B/lane global loads (L2-resident).
// ---------------------------------------------------------------------------

typedef unsigned short ushort_t;
typedef __bf16 bf16x8 __attribute__((ext_vector_type(8)));
typedef float  f32x4  __attribute__((ext_vector_type(4)));

#define E_EDGES 9900
#define NNODE   100
#define BATCH   32
#define HID     256
#define M_BIG   (BATCH * E_EDGES)   /* 316800 */
#define M_SMALL (BATCH * NNODE)     /* 3200   */

__device__ __forceinline__ float bf2f(ushort_t u) {
    union { unsigned int i; float f; } v; v.i = ((unsigned int)u) << 16; return v.f;
}
__device__ __forceinline__ ushort_t f2bf(float f) {
    union { float f; unsigned int i; } v; v.f = f;
    return (ushort_t)((v.i + 0x7fffu + ((v.i >> 16) & 1u)) >> 16);   // RNE
}
__device__ __forceinline__ float elu_f(float x) {
    return x > 0.f ? x : (expf(x) - 1.f);
}

// ---- weight convert+transpose: W[k][256] fp32 -> WT[256][K] bf16 ----------
__global__ __launch_bounds__(256)
void wcvt_kernel(const float* __restrict__ W, ushort_t* __restrict__ WT, int K)
{
    __shared__ float T[64][257];
    const int k0 = blockIdx.x * 64;
    const int t = threadIdx.x;
    for (int m = 0; m < 64; ++m) T[m][t] = W[(size_t)(k0 + m) * 256 + t];
    __syncthreads();
    ushort_t* dst = WT + (size_t)t * K + k0;
    for (int m = 0; m < 64; ++m) dst[m] = f2bf(T[m][t]);
}

// ---- small fp32 GEMM: Y[3200,256] = ELU(xscale*X@W + b), fp32 or bf16 out -
#define FMA_ROW(ri, xs) \
    acc[ri][0] = fmaf(xs, w.x, acc[ri][0]); \
    acc[ri][1] = fmaf(xs, w.y, acc[ri][1]); \
    acc[ri][2] = fmaf(xs, w.z, acc[ri][2]); \
    acc[ri][3] = fmaf(xs, w.w, acc[ri][3]);

template<bool OUTBF>
__global__ __launch_bounds__(256, 3)
void mlp_gemm_f32(const float* __restrict__ X, const float* __restrict__ W,
                  const float* __restrict__ bias,
                  float* __restrict__ Yf, ushort_t* __restrict__ Yb,
                  int K1, float xscale)
{
    __shared__ float Xs[32][68];
    __shared__ float Ws[32][256];
    const int tid = threadIdx.x;
    const int Rbase = blockIdx.x * 64;
    const int c0 = (tid & 63) * 4;
    const int r0 = (tid >> 6) * 16;
    const int r_st = tid & 63;
    const int kb = (tid >> 6) * 8;

    float acc[16][4];
    #pragma unroll
    for (int i = 0; i < 16; ++i)
        #pragma unroll
        for (int j = 0; j < 4; ++j) acc[i][j] = 0.f;

    const int nch = (K1 + 31) >> 5;
    for (int kc = 0; kc < nch; ++kc) {
        if (kc) __syncthreads();
        {
            int kg = kc * 32 + kb;
            const float* p = X + (size_t)(Rbase + r_st) * K1 + kg;
            float v[8];
            if (kg + 8 <= K1) {
                float4 a = *(const float4*)p;
                float4 b = *(const float4*)(p + 4);
                v[0]=a.x; v[1]=a.y; v[2]=a.z; v[3]=a.w;
                v[4]=b.x; v[5]=b.y; v[6]=b.z; v[7]=b.w;
            } else {
                #pragma unroll
                for (int j = 0; j < 8; ++j) v[j] = (kg + j < K1) ? p[j] : 0.f;
            }
            #pragma unroll
            for (int j = 0; j < 8; ++j) Xs[kb + j][r_st] = v[j];
        }
        #pragma unroll
        for (int m = 0; m < 8; ++m) {
            int f  = tid + m * 256;
            int kk = f >> 6;
            int cc = (f & 63) * 4;
            int kg = kc * 32 + kk;
            float4 w = (kg < K1) ? *(const float4*)&W[(size_t)kg * 256 + cc]
                                 : make_float4(0.f, 0.f, 0.f, 0.f);
            *(float4*)&Ws[kk][cc] = w;
        }
        __syncthreads();
        #pragma unroll 8
        for (int kk = 0; kk < 32; ++kk) {
            float4 w = *(const float4*)&Ws[kk][c0];
            #pragma unroll
            for (int i = 0; i < 4; ++i) {
                float4 x = *(const float4*)&Xs[kk][r0 + 4 * i];
                FMA_ROW(4 * i + 0, x.x)
                FMA_ROW(4 * i + 1, x.y)
                FMA_ROW(4 * i + 2, x.z)
                FMA_ROW(4 * i + 3, x.w)
            }
        }
    }
    float4 bv = *(const float4*)&bias[c0];
    #pragma unroll
    for (int i = 0; i < 16; ++i) {
        int R = Rbase + r0 + i;
        float o0 = elu_f(acc[i][0] * xscale + bv.x);
        float o1 = elu_f(acc[i][1] * xscale + bv.y);
        float o2 = elu_f(acc[i][2] * xscale + bv.z);
        float o3 = elu_f(acc[i][3] * xscale + bv.w);
        if (OUTBF) {
            ushort4 u;
            u.x = f2bf(o0); u.y = f2bf(o1); u.z = f2bf(o2); u.w = f2bf(o3);
            *(ushort4*)&Yb[(size_t)R * 256 + c0] = u;
        } else {
            *(float4*)&Yf[(size_t)R * 256 + c0] = make_float4(o0, o1, o2, o3);
        }
    }
}

// ---- fused 2-layer MFMA MLP over 64 edge rows -----------------------------
// MODE 2: L1 in = [h1b[send]|h1b[recv]] (K1=512); epilogue: e2n partials->aux
// MODE 3: L1 in = [h3b[send]|h3b[recv]|x2[R]] (K1=768); in-place; stats->aux
// Wave w: cols 64w..64w+63 (4 col-tiles), rows 0..63 (4 row-tiles).
// A staged in LDS (dbuf, XOR-quad swizzle); B frags direct from WT[col][K].
template<int MODE>
__global__ __launch_bounds__(256, 3)
void fused_mfma(const ushort_t* __restrict__ Gb,    // h1b/h3b [3200][256] bf16
                const ushort_t* __restrict__ X2,    // skip source (MODE 3)
                const ushort_t* __restrict__ W1T,   // [256][K1] bf16
                const float* __restrict__ bias1,
                const ushort_t* __restrict__ W2T,   // [256][256] bf16
                const float* __restrict__ bias2,
                ushort_t* __restrict__ Y,
                float* __restrict__ aux)
{
    constexpr int K1 = (MODE == 2) ? 512 : 768;
    constexpr int NST = K1 / 32;
    __shared__ ushort_t As[2][2048];     // 64 rows x 32 k, quad-swizzled
    __shared__ ushort_t Hb[64][264];     // hidden / output park (row stride 528B)
    __shared__ int offS[64], offR[64];

    const int tid = threadIdx.x;
    const int Rbase = blockIdx.x * 64;
    if (tid < 64) {
        int R = Rbase + tid;
        int b = R / E_EDGES;
        int e = R - b * E_EDGES;
        int i = e / 99;                       // receiver
        int kk = e - i * 99;
        int j = kk + (kk >= i ? 1 : 0);       // sender
        offS[tid] = (b * NNODE + j) * HID;
        offR[tid] = (b * NNODE + i) * HID;
    }
    __syncthreads();

    const int w = tid >> 6;          // wave id -> col block
    const int l = tid & 63;
    const int ln15 = l & 15;
    const int q = l >> 4;
    const int swz = ((q + ln15) & 3) * 8;     // A-frag LDS swizzle (16r drops out)
    const int s_row = tid & 63;               // staging row
    const int s_q   = w;                      // staging quad
    const int oS = offS[s_row], oR = offR[s_row];
    const ushort_t* x2row = (MODE == 3) ? (X2 + (size_t)(Rbase + s_row) * 256) : nullptr;

    auto stage = [&](int kcs, int bb) {
        int kg = kcs * 32 + s_q * 8;
        const ushort_t* src;
        if (MODE == 3 && kg >= 512) src = x2row + (kg - 512);
        else src = Gb + ((kg < 256) ? (oS + kg) : (oR + kg - 256));
        *(bf16x8*)&As[bb][s_row * 32 + (((s_q + s_row) & 3) * 8)] = *(const bf16x8*)src;
    };

    f32x4 acc[4][4];
    #pragma unroll
    for (int r = 0; r < 4; ++r)
        #pragma unroll
        for (int c = 0; c < 4; ++c)
            acc[r][c][0] = acc[r][c][1] = acc[r][c][2] = acc[r][c][3] = 0.f;

    // ---------------- layer 1: K1 steps of 32 ----------------
    stage(0, 0);
    __syncthreads();
    const ushort_t* pB1 = W1T + (size_t)(w * 64 + ln15) * K1 + q * 8;
    for (int kc = 0; kc < NST; ++kc) {
        int bb = kc & 1;
        if (kc + 1 < NST) stage(kc + 1, bb ^ 1);
        bf16x8 af[4], bf[4];
        #pragma unroll
        for (int r = 0; r < 4; ++r)
            af[r] = *(const bf16x8*)&As[bb][(16 * r + ln15) * 32 + swz];
        #pragma unroll
        for (int c = 0; c < 4; ++c)
            bf[c] = *(const bf16x8*)(pB1 + (size_t)(16 * c) * K1 + kc * 32);
        #pragma unroll
        for (int r = 0; r < 4; ++r)
            #pragma unroll
            for (int c = 0; c < 4; ++c)
                acc[r][c] = __builtin_amdgcn_mfma_f32_16x16x32_bf16(af[r], bf[c], acc[r][c], 0, 0, 0);
        __syncthreads();
    }

    // hidden = ELU(acc + b1) -> Hb
    {
        float bv[4];
        #pragma unroll
        for (int c = 0; c < 4; ++c) bv[c] = bias1[w * 64 + c * 16 + ln15];
        #pragma unroll
        for (int r = 0; r < 4; ++r)
            #pragma unroll
            for (int c = 0; c < 4; ++c) {
                #pragma unroll
                for (int reg = 0; reg < 4; ++reg) {
                    int row = 16 * r + q * 4 + reg;
                    Hb[row][w * 64 + c * 16 + ln15] = f2bf(elu_f(acc[r][c][reg] + bv[c]));
                }
            }
    }
    __syncthreads();

    // ---------------- layer 2: K=256, A from Hb --------------
    #pragma unroll
    for (int r = 0; r < 4; ++r)
        #pragma unroll
        for (int c = 0; c < 4; ++c)
            acc[r][c][0] = acc[r][c][1] = acc[r][c][2] = acc[r][c][3] = 0.f;

    const ushort_t* pB2 = W2T + (size_t)(w * 64 + ln15) * 256 + q * 8;
    for (int kc = 0; kc < 8; ++kc) {
        bf16x8 af[4], bf[4];
        #pragma unroll
        for (int r = 0; r < 4; ++r)
            af[r] = *(const bf16x8*)&Hb[16 * r + ln15][kc * 32 + q * 8];
        #pragma unroll
        for (int c = 0; c < 4; ++c)
            bf[c] = *(const bf16x8*)(pB2 + (size_t)(16 * c) * 256 + kc * 32);
        #pragma unroll
        for (int r = 0; r < 4; ++r)
            #pragma unroll
            for (int c = 0; c < 4; ++c)
                acc[r][c] = __builtin_amdgcn_mfma_f32_16x16x32_bf16(af[r], bf[c], acc[r][c], 0, 0, 0);
    }
    __syncthreads();    // all Hb reads done before overwrite

    // out = ELU(acc + b2) -> Hb (reuse), then coalesced global write
    {
        float bv[4];
        #pragma unroll
        for (int c = 0; c < 4; ++c) bv[c] = bias2[w * 64 + c * 16 + ln15];
        #pragma unroll
        for (int r = 0; r < 4; ++r)
            #pragma unroll
            for (int c = 0; c < 4; ++c) {
                #pragma unroll
                for (int reg = 0; reg < 4; ++reg) {
                    int row = 16 * r + q * 4 + reg;
                    Hb[row][w * 64 + c * 16 + ln15] = f2bf(elu_f(acc[r][c][reg] + bv[c]));
                }
            }
    }
    __syncthreads();

    #pragma unroll
    for (int m = 0; m < 8; ++m) {
        int ch = tid + m * 256;
        int row = ch >> 5;
        int o = (ch & 31) * 8;
        *(uint4*)&Y[((size_t)(Rbase + row)) * 256 + o] = *(const uint4*)&Hb[row][o];
    }

    // fused epilogue reductions over this block's 64 output rows
    {
        int c = tid;   // 0..255 = channel
        if (MODE == 2) {
            int bn = Rbase / 99;               // = b*100 + receiver
            int left = 99 - (Rbase - bn * 99);
            float s = 0.f;
            for (int r = 0; r < 64; ++r) {
                s += bf2f(Hb[r][c]);
                if (--left == 0) { atomicAdd(&aux[(size_t)bn * 256 + c], s); s = 0.f; ++bn; left = 99; }
            }
            atomicAdd(&aux[(size_t)bn * 256 + c], s);
        } else {
            float s = 0.f, q2 = 0.f;
            for (int r = 0; r < 64; ++r) {
                float v = bf2f(Hb[r][c]);
                s += v;
                q2 = fmaf(v, v, q2);
            }
            atomicAdd(&aux[c], s);
            atomicAdd(&aux[256 + c], q2);
        }
    }
}

// ---- fold BN + fc into Wfold[256][2], bfold[2] ----------------------------
__global__ __launch_bounds__(256)
void fold_kernel(const float* __restrict__ stats,
                 const float* __restrict__ gamma, const float* __restrict__ beta,
                 const float* __restrict__ fcW, const float* __restrict__ fcb,
                 float* __restrict__ fold)
{
    __shared__ float red0[256], red1[256];
    int c = threadIdx.x;
    float mean  = stats[c] * (1.f / M_BIG);
    float var   = stats[256 + c] * (1.f / M_BIG) - mean * mean;
    float inv   = rsqrtf(var + 1e-5f);
    float scale = inv * gamma[c];
    float sh    = beta[c] - mean * scale;
    float w0 = fcW[c * 2 + 0], w1 = fcW[c * 2 + 1];
    fold[c * 2 + 0] = scale * w0;
    fold[c * 2 + 1] = scale * w1;
    red0[c] = sh * w0;
    red1[c] = sh * w1;
    __syncthreads();
    for (int off = 128; off > 0; off >>= 1) {
        if (c < off) { red0[c] += red0[c + off]; red1[c] += red1[c + off]; }
        __syncthreads();
    }
    if (c == 0) {
        fold[512] = red0[0] + fcb[0];
        fold[513] = red1[0] + fcb[1];
    }
}

// ---- final: out[R][2] = x4_row . Wfold + bfold  (wave per row) ------------
__global__ __launch_bounds__(256)
void final_kernel(const ushort_t* __restrict__ x4, const float* __restrict__ fold,
                  float* __restrict__ out)
{
    int tid  = threadIdx.x;
    int lane = tid & 63;
    int wave = tid >> 6;
    int R = blockIdx.x * 4 + wave;
    int c0 = lane * 4;
    union { uint2 q; ushort_t s[4]; } u;
    u.q = *(const uint2*)(x4 + (size_t)R * 256 + c0);
    float a0 = 0.f, a1 = 0.f;
    #pragma unroll
    for (int j = 0; j < 4; ++j) {
        float v = bf2f(u.s[j]);
        a0 = fmaf(v, fold[(c0 + j) * 2 + 0], a0);
        a1 = fmaf(v, fold[(c0 + j) * 2 + 1], a1);
    }
    #pragma unroll
    for (int off = 32; off > 0; off >>= 1) {
        a0 += __shfl_down(a0, off);
        a1 += __shfl_down(a1, off);
    }
    if (lane == 0) {
        out[(size_t)R * 2 + 0] = a0 + fold[512];
        out[(size_t)R * 2 + 1] = a1 + fold[513];
    }
}

extern "C" void kernel_launch(void* const* d_in, const int* in_sizes, int n_in,
                              void* d_out, int out_size, void* d_ws, size_t ws_size,
                              hipStream_t stream)
{
    (void)in_sizes; (void)n_in; (void)out_size; (void)ws_size;

    const float* inputs = (const float*)d_in[0];
    const float* m1W1 = (const float*)d_in[3];
    const float* m1b1 = (const float*)d_in[4];
    const float* m1W2 = (const float*)d_in[5];
    const float* m1b2 = (const float*)d_in[6];
    const float* m2W1 = (const float*)d_in[7];
    const float* m2b1 = (const float*)d_in[8];
    const float* m2W2 = (const float*)d_in[9];
    const float* m2b2 = (const float*)d_in[10];
    const float* m3W1 = (const float*)d_in[11];
    const float* m3b1 = (const float*)d_in[12];
    const float* m3W2 = (const float*)d_in[13];
    const float* m3b2 = (const float*)d_in[14];
    const float* m4W1 = (const float*)d_in[15];
    const float* m4b1 = (const float*)d_in[16];
    const float* m4W2 = (const float*)d_in[17];
    const float* m4b2 = (const float*)d_in[18];
    const float* gamma = (const float*)d_in[19];
    const float* beta  = (const float*)d_in[20];
    const float* fcW   = (const float*)d_in[21];
    const float* fcb   = (const float*)d_in[22];
    float* out = (float*)d_out;

    // ---- workspace layout (~171.4 MB) ----
    char* ws = (char*)d_ws;
    const size_t BIGB  = (size_t)M_BIG * 256 * 2;       // 162,201,600
    const size_t SMALL = (size_t)M_SMALL * 256 * 4;     // 3,276,800
    const size_t HB    = (size_t)M_SMALL * 256 * 2;     // 1,638,400
    ushort_t* bigX   = (ushort_t*)ws;                   // x2 then x4 (in-place)
    float*    bufP   = (float*)(ws + BIGB);
    ushort_t* hbuf   = (ushort_t*)(ws + BIGB + SMALL);            // h1b then h3b
    float*    incoming = (float*)(ws + BIGB + SMALL + HB);
    float*    stats  = (float*)(ws + BIGB + 2 * SMALL + HB);      // 512 f32
    float*    fold   = stats + 512;                                // 514 f32
    ushort_t* w1t    = (ushort_t*)(ws + BIGB + 2 * SMALL + HB + 8192);
    ushort_t* w2t    = w1t + 512 * 256;
    ushort_t* w4at   = w2t + 256 * 256;
    ushort_t* w4bt   = w4at + 768 * 256;

    hipMemsetAsync(stats, 0, 2048, stream);
    hipMemsetAsync(incoming, 0, SMALL, stream);

    dim3 blk(256);
    // weight convert+transpose (bf16, [col][K])
    wcvt_kernel<<< 8, blk, 0, stream>>>(m2W1, w1t, 512);
    wcvt_kernel<<< 4, blk, 0, stream>>>(m2W2, w2t, 256);
    wcvt_kernel<<<12, blk, 0, stream>>>(m4W1, w4at, 768);
    wcvt_kernel<<< 4, blk, 0, stream>>>(m4W2, w4bt, 256);

    // MLP1: inputs[3200,200] -> bufP (f32) -> hbuf (bf16 h1)
    mlp_gemm_f32<false><<<M_SMALL / 64, blk, 0, stream>>>(inputs, m1W1, m1b1, bufP, nullptr, 200, 1.f);
    mlp_gemm_f32<true ><<<M_SMALL / 64, blk, 0, stream>>>(bufP,   m1W2, m1b2, nullptr, hbuf, 256, 1.f);
    // fused MLP2 (MFMA): gather h1b -> x2 (bigX); epilogue: e2n sums -> incoming
    fused_mfma<2><<<M_BIG / 64, blk, 0, stream>>>(hbuf, bigX, w1t, m2b1, w2t, m2b2, bigX, incoming);
    // MLP3: incoming/9900 -> bufP (f32) -> hbuf (bf16 h3)
    mlp_gemm_f32<false><<<M_SMALL / 64, blk, 0, stream>>>(incoming, m3W1, m3b1, bufP, nullptr, 256, 1.f / 9900.f);
    mlp_gemm_f32<true ><<<M_SMALL / 64, blk, 0, stream>>>(bufP,     m3W2, m3b2, nullptr, hbuf, 256, 1.f);
    // fused MLP4 (MFMA): gather h3b + skip x2 -> x4 in-place; epilogue: stats
    fused_mfma<3><<<M_BIG / 64, blk, 0, stream>>>(hbuf, bigX, w4at, m4b1, w4bt, m4b2, bigX, stats);
    // BN fold -> final linear
    fold_kernel<<<1, blk, 0, stream>>>(stats, gamma, beta, fcW, fcb, fold);
    final_kernel<<<M_BIG / 4, blk, 0, stream>>>(bigX, fold, out);
}